// Round 2
// baseline (357.305 us; speedup 1.0000x reference)
//
#include <hip/hip_runtime.h>
#include <math.h>

#define TAU_F       0.1f
#define EPS_NORM_F  1e-12f
#define EPS_DENOM_F 1e-8f

__device__ __forceinline__ float dot4(float4 a, float4 b) {
    return a.x * b.x + a.y * b.y + a.z * b.z + a.w * b.w;
}

// -----------------------------------------------------------------------------
// Single fused kernel.
// Phase 1: wave-per-row cos(row, anchor) for hard_negatives (accumulate
//          sum(exp(cos/tau))) and positives (store cos to ws).
//          Waves 0..2*n_mix-1 additionally handle one synthetic negative each,
//          recomputing the needed cosines from raw rows (self-contained).
// Phase 2: last block (threadfence-reduction pattern) sums the 2048 block
//          partials -> S, then reduces the positive loss and writes out.
// -----------------------------------------------------------------------------
__global__ void __launch_bounds__(256) fused_kernel(
        const float* __restrict__ anchor,
        const float* __restrict__ pos,
        const float* __restrict__ hn,
        const int* __restrict__ mix_idx,
        const int* __restrict__ idx_a,
        const int* __restrict__ idx_b,
        const float* __restrict__ alpha_raw,
        const float* __restrict__ beta_raw,
        float* __restrict__ out,
        double* __restrict__ block_sums,
        float* __restrict__ cos_p,
        unsigned* __restrict__ ctr,
        int n_hard, int n_pos, int n_mix) {
    const int lane = threadIdx.x & 63;
    const int wib  = threadIdx.x >> 6;
    const int wpb  = blockDim.x >> 6;
    const int wid  = blockIdx.x * wpb + wib;
    const int nw   = gridDim.x * wpb;

    // Anchor slice: the 64 lanes tile all 512 floats (2 float4 each).
    const float4* a4 = (const float4*)anchor;
    const float4 a0 = a4[lane];
    const float4 a1 = a4[lane + 64];
    float na2 = dot4(a0, a0) + dot4(a1, a1);
    #pragma unroll
    for (int o = 32; o > 0; o >>= 1) na2 += __shfl_xor(na2, o, 64);
    const float na = fmaxf(sqrtf(na2), EPS_NORM_F);

    float local_exp = 0.0f;   // lane-uniform after each butterfly reduce

    // ---- Phase 1: grid-stride over all rows (hard negs first, then pos) ----
    const int total = n_hard + n_pos;
    for (int r = wid; r < total; r += nw) {
        const bool is_h = (r < n_hard);
        const float4* row = is_h ? (const float4*)hn + (size_t)r * 128
                                 : (const float4*)pos + (size_t)(r - n_hard) * 128;
        const float4 v0 = row[lane];
        const float4 v1 = row[lane + 64];
        float s  = dot4(v0, a0) + dot4(v1, a1);
        float n2 = dot4(v0, v0) + dot4(v1, v1);
        #pragma unroll
        for (int o = 32; o > 0; o >>= 1) {
            s  += __shfl_xor(s,  o, 64);
            n2 += __shfl_xor(n2, o, 64);
        }
        const float nrm  = fmaxf(sqrtf(n2), EPS_NORM_F);
        const float cosv = s / (nrm * na);
        if (is_h) {
            local_exp += expf(cosv / TAU_F);
        } else if (lane == 0) {
            cos_p[r - n_hard] = cosv;
        }
    }

    // ---- Synthetic negatives: one wave per item, self-contained math ----
    if (wid < n_mix) {
        const int j = wid;
        const float4* R = (const float4*)hn + (size_t)mix_idx[j] * 128;
        const float4 v0 = R[lane], v1 = R[lane + 64];
        float s  = dot4(v0, a0) + dot4(v1, a1);
        float n2 = dot4(v0, v0) + dot4(v1, v1);
        #pragma unroll
        for (int o = 32; o > 0; o >>= 1) {
            s  += __shfl_xor(s,  o, 64);
            n2 += __shfl_xor(n2, o, 64);
        }
        const float nrm = fmaxf(sqrtf(n2), EPS_NORM_F);
        const float c   = s / (nrm * na);
        const float al  = alpha_raw[j] * 0.4f + 0.1f;
        const float num  = (1.0f - al) * c + al;
        const float den2 = (1.0f - al) * (1.0f - al) + al * al
                         + 2.0f * al * (1.0f - al) * c;
        const float cosm = num / fmaxf(sqrtf(den2), EPS_NORM_F);
        local_exp += expf(cosm / TAU_F);
    } else if (wid < 2 * n_mix) {
        const int k  = wid - n_mix;
        const float4* A = (const float4*)hn + (size_t)idx_a[k] * 128;
        const float4* B = (const float4*)hn + (size_t)idx_b[k] * 128;
        const float4 x0 = A[lane], x1 = A[lane + 64];
        const float4 y0 = B[lane], y1 = B[lane + 64];
        float sa  = dot4(x0, a0) + dot4(x1, a1);
        float sb  = dot4(y0, a0) + dot4(y1, a1);
        float d   = dot4(x0, y0) + dot4(x1, y1);
        float nA2 = dot4(x0, x0) + dot4(x1, x1);
        float nB2 = dot4(y0, y0) + dot4(y1, y1);
        #pragma unroll
        for (int o = 32; o > 0; o >>= 1) {
            sa  += __shfl_xor(sa,  o, 64);
            sb  += __shfl_xor(sb,  o, 64);
            d   += __shfl_xor(d,   o, 64);
            nA2 += __shfl_xor(nA2, o, 64);
            nB2 += __shfl_xor(nB2, o, 64);
        }
        const float nA  = fmaxf(sqrtf(nA2), EPS_NORM_F);
        const float nB  = fmaxf(sqrtf(nB2), EPS_NORM_F);
        const float ca  = sa / (nA * na);
        const float cb  = sb / (nB * na);
        const float dab = d  / (nA * nB);
        const float be  = beta_raw[k] * 0.4f + 0.3f;
        const float num  = be * ca + (1.0f - be) * cb;
        const float den2 = be * be + (1.0f - be) * (1.0f - be)
                         + 2.0f * be * (1.0f - be) * dab;
        const float cosm = num / fmaxf(sqrtf(den2), EPS_NORM_F);
        local_exp += expf(cosm / TAU_F);
    }

    // ---- Block partial -> slot, arrival counter, last-block finishes ----
    __shared__ float sred[16];
    __shared__ int   is_last;
    if (lane == 0) sred[wib] = local_exp;
    __syncthreads();
    if (threadIdx.x == 0) {
        float t = 0.0f;
        for (int i = 0; i < wpb; ++i) t += sred[i];
        block_sums[blockIdx.x] = (double)t;
        __threadfence();   // release: publish block_sums + this block's cos_p
        const unsigned old = __hip_atomic_fetch_add(
            ctr, 1u, __ATOMIC_ACQ_REL, __HIP_MEMORY_SCOPE_AGENT);
        is_last = (old == (unsigned)gridDim.x - 1u) ? 1 : 0;
    }
    __syncthreads();
    if (!is_last) return;

    __threadfence();       // acquire: see other blocks' block_sums + cos_p

    __shared__ double dred[256];
    double acc = 0.0;
    for (int i = threadIdx.x; i < (int)gridDim.x; i += blockDim.x)
        acc += block_sums[i];
    dred[threadIdx.x] = acc;
    __syncthreads();
    for (int sft = 128; sft > 0; sft >>= 1) {
        if (threadIdx.x < sft) dred[threadIdx.x] += dred[threadIdx.x + sft];
        __syncthreads();
    }
    const float S = (float)dred[0];
    __syncthreads();

    double lacc = 0.0;
    for (int i = threadIdx.x; i < n_pos; i += blockDim.x) {
        const float pv = expf(cos_p[i] / TAU_F);
        lacc += (double)(-logf(pv / (pv + S + EPS_DENOM_F)));
    }
    dred[threadIdx.x] = lacc;
    __syncthreads();
    for (int sft = 128; sft > 0; sft >>= 1) {
        if (threadIdx.x < sft) dred[threadIdx.x] += dred[threadIdx.x + sft];
        __syncthreads();
    }
    if (threadIdx.x == 0) out[0] = (float)(dred[0] / (double)n_pos);
}

extern "C" void kernel_launch(void* const* d_in, const int* in_sizes, int n_in,
                              void* d_out, int out_size, void* d_ws, size_t ws_size,
                              hipStream_t stream) {
    const float* anchor    = (const float*)d_in[0];
    const float* positives = (const float*)d_in[1];
    const float* hardnegs  = (const float*)d_in[2];
    const int*   mix_idx   = (const int*)d_in[3];
    const int*   idx_a     = (const int*)d_in[4];
    const int*   idx_b     = (const int*)d_in[5];
    const float* alpha_raw = (const float*)d_in[6];
    const float* beta_raw  = (const float*)d_in[7];

    const int D      = in_sizes[0];          // 512
    const int n_pos  = in_sizes[1] / D;      // 8192
    const int n_hard = in_sizes[2] / D;      // 65536
    const int n_mix  = in_sizes[3];          // 64

    const int GRID = 2048;                   // 8 blocks/CU x 256 CUs, co-resident

    // ws layout: [0,4) arrival ctr | [1024, 1024+GRID*8) block_sums | cos_p
    char*     ws         = (char*)d_ws;
    unsigned* ctr        = (unsigned*)ws;
    double*   block_sums = (double*)(ws + 1024);
    float*    cos_p      = (float*)(ws + 1024 + (size_t)GRID * sizeof(double));

    hipMemsetAsync(ctr, 0, sizeof(unsigned), stream);

    fused_kernel<<<GRID, 256, 0, stream>>>(anchor, positives, hardnegs,
                                           mix_idx, idx_a, idx_b,
                                           alpha_raw, beta_raw,
                                           (float*)d_out, block_sums, cos_p, ctr,
                                           n_hard, n_pos, n_mix);
}

// Round 3
// 234.435 us; speedup vs baseline: 1.5241x; 1.5241x over previous
//
#include <hip/hip_runtime.h>
#include <math.h>

#define TAU_F       0.1f
#define EPS_NORM_F  1e-12f
#define EPS_DENOM_F 1e-8f

__device__ __forceinline__ float dot4(float4 a, float4 b) {
    return a.x * b.x + a.y * b.y + a.z * b.z + a.w * b.w;
}

// -----------------------------------------------------------------------------
// Main kernel: wave-per-row cosine vs anchor, 3 rows in flight per iteration.
// Wave w owns 9 contiguous rows [w*9, w*9+9) of the 73728 (hard||pos) rows.
// Each iteration: issue 6 independent float4 loads (6 KB in flight), compute
// 3 (dot, norm2) pairs, reduce via 6 interleaved butterfly chains.
// Hard-neg rows accumulate exp(cos/tau); positive rows store cos to ws.
// Waves 0..2*n_mix-1 also compute one synthetic negative (self-contained).
// One f64 atomicAdd per block.
// -----------------------------------------------------------------------------
__global__ void __launch_bounds__(256) main_kernel(
        const float* __restrict__ anchor,
        const float* __restrict__ pos,
        const float* __restrict__ hn,
        const int* __restrict__ mix_idx,
        const int* __restrict__ idx_a,
        const int* __restrict__ idx_b,
        const float* __restrict__ alpha_raw,
        const float* __restrict__ beta_raw,
        double* __restrict__ S_acc,
        float* __restrict__ cos_p,
        int n_hard, int n_pos, int n_mix) {
    const int lane = threadIdx.x & 63;
    const int wib  = threadIdx.x >> 6;
    const int wpb  = blockDim.x >> 6;
    const int wid  = blockIdx.x * wpb + wib;
    const int nw   = gridDim.x * wpb;

    // Anchor slice: 64 lanes tile all 512 floats (2 float4 each).
    const float4* a4 = (const float4*)anchor;
    const float4 a0 = a4[lane];
    const float4 a1 = a4[lane + 64];
    float na2 = dot4(a0, a0) + dot4(a1, a1);
    #pragma unroll
    for (int o = 32; o > 0; o >>= 1) na2 += __shfl_xor(na2, o, 64);
    const float na = fmaxf(sqrtf(na2), EPS_NORM_F);

    const int total = n_hard + n_pos;
    const int per   = (total + nw - 1) / nw;     // rows per wave (9)
    const int base  = wid * per;

    float local_exp = 0.0f;   // lane-uniform after each butterfly reduce

    for (int it = 0; it < per; it += 3) {
        const int r0 = base + it;
        const int r1 = r0 + 1;
        const int r2 = r0 + 2;
        // Clamp for generality (exact division in this problem: guards all true).
        const int c0 = r0 < total ? r0 : 0;
        const int c1 = r1 < total ? r1 : 0;
        const int c2 = r2 < total ? r2 : 0;
        const float4* p0 = (c0 < n_hard) ? (const float4*)hn  + (size_t)c0 * 128
                                         : (const float4*)pos + (size_t)(c0 - n_hard) * 128;
        const float4* p1 = (c1 < n_hard) ? (const float4*)hn  + (size_t)c1 * 128
                                         : (const float4*)pos + (size_t)(c1 - n_hard) * 128;
        const float4* p2 = (c2 < n_hard) ? (const float4*)hn  + (size_t)c2 * 128
                                         : (const float4*)pos + (size_t)(c2 - n_hard) * 128;
        // Issue all six loads before any use.
        const float4 v00 = p0[lane], v01 = p0[lane + 64];
        const float4 v10 = p1[lane], v11 = p1[lane + 64];
        const float4 v20 = p2[lane], v21 = p2[lane + 64];

        float s0 = dot4(v00, a0) + dot4(v01, a1);
        float q0 = dot4(v00, v00) + dot4(v01, v01);
        float s1 = dot4(v10, a0) + dot4(v11, a1);
        float q1 = dot4(v10, v10) + dot4(v11, v11);
        float s2 = dot4(v20, a0) + dot4(v21, a1);
        float q2 = dot4(v20, v20) + dot4(v21, v21);

        // Six interleaved butterfly chains (depth 6 each).
        #pragma unroll
        for (int o = 32; o > 0; o >>= 1) {
            s0 += __shfl_xor(s0, o, 64);  q0 += __shfl_xor(q0, o, 64);
            s1 += __shfl_xor(s1, o, 64);  q1 += __shfl_xor(q1, o, 64);
            s2 += __shfl_xor(s2, o, 64);  q2 += __shfl_xor(q2, o, 64);
        }

        const float cos0 = s0 / (fmaxf(sqrtf(q0), EPS_NORM_F) * na);
        const float cos1 = s1 / (fmaxf(sqrtf(q1), EPS_NORM_F) * na);
        const float cos2 = s2 / (fmaxf(sqrtf(q2), EPS_NORM_F) * na);

        // Wave-uniform branches (r*, n_hard uniform across the wave).
        if (r0 < total) {
            if (r0 < n_hard) local_exp += expf(cos0 / TAU_F);
            else if (lane == 0) cos_p[r0 - n_hard] = cos0;
        }
        if (r1 < total) {
            if (r1 < n_hard) local_exp += expf(cos1 / TAU_F);
            else if (lane == 0) cos_p[r1 - n_hard] = cos1;
        }
        if (r2 < total) {
            if (r2 < n_hard) local_exp += expf(cos2 / TAU_F);
            else if (lane == 0) cos_p[r2 - n_hard] = cos2;
        }
    }

    // ---- Synthetic negatives: one wave per item, self-contained math ----
    if (wid < n_mix) {
        const int j = wid;
        const float4* R = (const float4*)hn + (size_t)mix_idx[j] * 128;
        const float4 v0 = R[lane], v1 = R[lane + 64];
        float s  = dot4(v0, a0) + dot4(v1, a1);
        float n2 = dot4(v0, v0) + dot4(v1, v1);
        #pragma unroll
        for (int o = 32; o > 0; o >>= 1) {
            s  += __shfl_xor(s,  o, 64);
            n2 += __shfl_xor(n2, o, 64);
        }
        const float nrm = fmaxf(sqrtf(n2), EPS_NORM_F);
        const float c   = s / (nrm * na);
        const float al  = alpha_raw[j] * 0.4f + 0.1f;
        const float num  = (1.0f - al) * c + al;
        const float den2 = (1.0f - al) * (1.0f - al) + al * al
                         + 2.0f * al * (1.0f - al) * c;
        const float cosm = num / fmaxf(sqrtf(den2), EPS_NORM_F);
        local_exp += expf(cosm / TAU_F);
    } else if (wid < 2 * n_mix) {
        const int k  = wid - n_mix;
        const float4* A = (const float4*)hn + (size_t)idx_a[k] * 128;
        const float4* B = (const float4*)hn + (size_t)idx_b[k] * 128;
        const float4 x0 = A[lane], x1 = A[lane + 64];
        const float4 y0 = B[lane], y1 = B[lane + 64];
        float sa  = dot4(x0, a0) + dot4(x1, a1);
        float sb  = dot4(y0, a0) + dot4(y1, a1);
        float d   = dot4(x0, y0) + dot4(x1, y1);
        float nA2 = dot4(x0, x0) + dot4(x1, x1);
        float nB2 = dot4(y0, y0) + dot4(y1, y1);
        #pragma unroll
        for (int o = 32; o > 0; o >>= 1) {
            sa  += __shfl_xor(sa,  o, 64);
            sb  += __shfl_xor(sb,  o, 64);
            d   += __shfl_xor(d,   o, 64);
            nA2 += __shfl_xor(nA2, o, 64);
            nB2 += __shfl_xor(nB2, o, 64);
        }
        const float nA  = fmaxf(sqrtf(nA2), EPS_NORM_F);
        const float nB  = fmaxf(sqrtf(nB2), EPS_NORM_F);
        const float ca  = sa / (nA * na);
        const float cb  = sb / (nB * na);
        const float dab = d  / (nA * nB);
        const float be  = beta_raw[k] * 0.4f + 0.3f;
        const float num  = be * ca + (1.0f - be) * cb;
        const float den2 = be * be + (1.0f - be) * (1.0f - be)
                         + 2.0f * be * (1.0f - be) * dab;
        const float cosm = num / fmaxf(sqrtf(den2), EPS_NORM_F);
        local_exp += expf(cosm / TAU_F);
    }

    // ---- Block partial -> one f64 atomic (round-1 pattern, known-correct) ----
    __shared__ float sred[16];
    if (lane == 0) sred[wib] = local_exp;
    __syncthreads();
    if (threadIdx.x == 0) {
        float t = 0.0f;
        for (int i = 0; i < wpb; ++i) t += sred[i];
        atomicAdd(S_acc, (double)t);
    }
}

// -----------------------------------------------------------------------------
// Finish kernel (1 block): loss = mean_i [ -log(pv_i / (pv_i + S + 1e-8)) ].
// -----------------------------------------------------------------------------
__global__ void __launch_bounds__(256) finish_kernel(
        const float* __restrict__ cos_p,
        const double* __restrict__ S_acc,
        float* __restrict__ out,
        int n_pos) {
    __shared__ double sred[256];
    const float S = (float)S_acc[0];
    double acc = 0.0;
    for (int i = threadIdx.x; i < n_pos; i += blockDim.x) {
        const float pv = expf(cos_p[i] / TAU_F);
        acc += (double)(-logf(pv / (pv + S + EPS_DENOM_F)));
    }
    sred[threadIdx.x] = acc;
    __syncthreads();
    for (int s = blockDim.x >> 1; s > 0; s >>= 1) {
        if (threadIdx.x < (unsigned)s) sred[threadIdx.x] += sred[threadIdx.x + s];
        __syncthreads();
    }
    if (threadIdx.x == 0) out[0] = (float)(sred[0] / (double)n_pos);
}

extern "C" void kernel_launch(void* const* d_in, const int* in_sizes, int n_in,
                              void* d_out, int out_size, void* d_ws, size_t ws_size,
                              hipStream_t stream) {
    const float* anchor    = (const float*)d_in[0];
    const float* positives = (const float*)d_in[1];
    const float* hardnegs  = (const float*)d_in[2];
    const int*   mix_idx   = (const int*)d_in[3];
    const int*   idx_a     = (const int*)d_in[4];
    const int*   idx_b     = (const int*)d_in[5];
    const float* alpha_raw = (const float*)d_in[6];
    const float* beta_raw  = (const float*)d_in[7];

    const int D      = in_sizes[0];          // 512
    const int n_pos  = in_sizes[1] / D;      // 8192
    const int n_hard = in_sizes[2] / D;      // 65536
    const int n_mix  = in_sizes[3];          // 64

    // ws layout: [0,8) f64 S accumulator | [1024, ...) cos_p
    char*   ws    = (char*)d_ws;
    double* S_acc = (double*)ws;
    float*  cos_p = (float*)(ws + 1024);

    hipMemsetAsync(S_acc, 0, sizeof(double), stream);

    // 2048 blocks x 4 waves = 8192 waves; 9 contiguous rows per wave.
    main_kernel<<<2048, 256, 0, stream>>>(anchor, positives, hardnegs,
                                          mix_idx, idx_a, idx_b,
                                          alpha_raw, beta_raw,
                                          S_acc, cos_p, n_hard, n_pos, n_mix);

    finish_kernel<<<1, 256, 0, stream>>>(cos_p, S_acc, (float*)d_out, n_pos);
}

// Round 4
// 221.367 us; speedup vs baseline: 1.6141x; 1.0590x over previous
//
#include <hip/hip_runtime.h>
#include <math.h>

#define TAU_F       0.1f
#define EPS_NORM_F  1e-12f
#define EPS_DENOM_F 1e-8f

__device__ __forceinline__ float dot4(float4 a, float4 b) {
    return a.x * b.x + a.y * b.y + a.z * b.z + a.w * b.w;
}

__device__ __forceinline__ const float4* rowptr(int r, int n_hard,
        const float4* __restrict__ hn4, const float4* __restrict__ pos4) {
    return (r < n_hard) ? hn4 + (size_t)r * 128
                        : pos4 + (size_t)(r - n_hard) * 128;
}

// Reduce three rows' (dot, norm2) via 6 interleaved butterfly chains, then
// dispose each row (hard-neg: accumulate exp; positive: lane0 stores cos).
// Expression forms identical to the rounds that passed with absmax == 0.
__device__ __forceinline__ void reduce3(
        int r0, int r1, int r2, int n_hard,
        float4 v00, float4 v01, float4 v10, float4 v11, float4 v20, float4 v21,
        float4 a0, float4 a1, float na, int lane,
        float& local_exp, float* __restrict__ cos_p) {
    float s0 = dot4(v00, a0) + dot4(v01, a1);
    float q0 = dot4(v00, v00) + dot4(v01, v01);
    float s1 = dot4(v10, a0) + dot4(v11, a1);
    float q1 = dot4(v10, v10) + dot4(v11, v11);
    float s2 = dot4(v20, a0) + dot4(v21, a1);
    float q2 = dot4(v20, v20) + dot4(v21, v21);
    #pragma unroll
    for (int o = 32; o > 0; o >>= 1) {
        s0 += __shfl_xor(s0, o, 64);  q0 += __shfl_xor(q0, o, 64);
        s1 += __shfl_xor(s1, o, 64);  q1 += __shfl_xor(q1, o, 64);
        s2 += __shfl_xor(s2, o, 64);  q2 += __shfl_xor(q2, o, 64);
    }
    const float c0 = s0 / (fmaxf(sqrtf(q0), EPS_NORM_F) * na);
    const float c1 = s1 / (fmaxf(sqrtf(q1), EPS_NORM_F) * na);
    const float c2 = s2 / (fmaxf(sqrtf(q2), EPS_NORM_F) * na);
    if (r0 < n_hard) local_exp += expf(c0 / TAU_F);
    else if (lane == 0) cos_p[r0 - n_hard] = c0;
    if (r1 < n_hard) local_exp += expf(c1 / TAU_F);
    else if (lane == 0) cos_p[r1 - n_hard] = c1;
    if (r2 < n_hard) local_exp += expf(c2 / TAU_F);
    else if (lane == 0) cos_p[r2 - n_hard] = c2;
}

// -----------------------------------------------------------------------------
// Main kernel. Wave w owns 9 contiguous rows; hot path is a straight-line
// software pipeline: load rows 0-5, reduce 0-2 (rows 3-5 in flight), load 6-8,
// reduce 3-5, reduce 6-8. Waves 0..2*n_mix-1 also compute one synthetic
// negative. Each block writes its partial sum to block_sums[blockIdx.x]
// (no atomics, no init required).
// -----------------------------------------------------------------------------
__global__ void __launch_bounds__(256) main_kernel(
        const float* __restrict__ anchor,
        const float* __restrict__ pos,
        const float* __restrict__ hn,
        const int* __restrict__ mix_idx,
        const int* __restrict__ idx_a,
        const int* __restrict__ idx_b,
        const float* __restrict__ alpha_raw,
        const float* __restrict__ beta_raw,
        double* __restrict__ block_sums,
        float* __restrict__ cos_p,
        int n_hard, int n_pos, int n_mix) {
    const int lane = threadIdx.x & 63;
    const int wib  = threadIdx.x >> 6;
    const int wpb  = blockDim.x >> 6;
    const int wid  = blockIdx.x * wpb + wib;
    const int nw   = gridDim.x * wpb;

    const float4* hn4  = (const float4*)hn;
    const float4* pos4 = (const float4*)pos;

    // Anchor slice: 64 lanes tile all 512 floats (2 float4 each).
    const float4* a4 = (const float4*)anchor;
    const float4 a0 = a4[lane];
    const float4 a1 = a4[lane + 64];
    float na2 = dot4(a0, a0) + dot4(a1, a1);
    #pragma unroll
    for (int o = 32; o > 0; o >>= 1) na2 += __shfl_xor(na2, o, 64);
    const float na = fmaxf(sqrtf(na2), EPS_NORM_F);

    const int total = n_hard + n_pos;
    const int per   = (total + nw - 1) / nw;
    const int base  = wid * per;

    float local_exp = 0.0f;   // lane-uniform after each butterfly reduce

    if (per == 9 && base + 9 <= total) {
        // ---- hot path: straight-line 9-row pipeline ----
        const float4* P0 = rowptr(base + 0, n_hard, hn4, pos4);
        const float4* P1 = rowptr(base + 1, n_hard, hn4, pos4);
        const float4* P2 = rowptr(base + 2, n_hard, hn4, pos4);
        const float4* P3 = rowptr(base + 3, n_hard, hn4, pos4);
        const float4* P4 = rowptr(base + 4, n_hard, hn4, pos4);
        const float4* P5 = rowptr(base + 5, n_hard, hn4, pos4);
        float4 A00 = P0[lane], A01 = P0[lane + 64];
        float4 A10 = P1[lane], A11 = P1[lane + 64];
        float4 A20 = P2[lane], A21 = P2[lane + 64];
        float4 B00 = P3[lane], B01 = P3[lane + 64];
        float4 B10 = P4[lane], B11 = P4[lane + 64];
        float4 B20 = P5[lane], B21 = P5[lane + 64];

        reduce3(base + 0, base + 1, base + 2, n_hard,
                A00, A01, A10, A11, A20, A21, a0, a1, na, lane,
                local_exp, cos_p);

        const float4* P6 = rowptr(base + 6, n_hard, hn4, pos4);
        const float4* P7 = rowptr(base + 7, n_hard, hn4, pos4);
        const float4* P8 = rowptr(base + 8, n_hard, hn4, pos4);
        A00 = P6[lane]; A01 = P6[lane + 64];
        A10 = P7[lane]; A11 = P7[lane + 64];
        A20 = P8[lane]; A21 = P8[lane + 64];

        reduce3(base + 3, base + 4, base + 5, n_hard,
                B00, B01, B10, B11, B20, B21, a0, a1, na, lane,
                local_exp, cos_p);

        reduce3(base + 6, base + 7, base + 8, n_hard,
                A00, A01, A10, A11, A20, A21, a0, a1, na, lane,
                local_exp, cos_p);
    } else {
        // ---- generic fallback (unused for the benchmark shape) ----
        for (int it = 0; it < per; ++it) {
            const int r = base + it;
            if (r >= total) break;
            const float4* P = rowptr(r, n_hard, hn4, pos4);
            const float4 v0 = P[lane], v1 = P[lane + 64];
            float s  = dot4(v0, a0) + dot4(v1, a1);
            float q  = dot4(v0, v0) + dot4(v1, v1);
            #pragma unroll
            for (int o = 32; o > 0; o >>= 1) {
                s += __shfl_xor(s, o, 64);  q += __shfl_xor(q, o, 64);
            }
            const float c = s / (fmaxf(sqrtf(q), EPS_NORM_F) * na);
            if (r < n_hard) local_exp += expf(c / TAU_F);
            else if (lane == 0) cos_p[r - n_hard] = c;
        }
    }

    // ---- Synthetic negatives: one wave per item, self-contained math ----
    if (wid < n_mix) {
        const int j = wid;
        const float4* R = hn4 + (size_t)mix_idx[j] * 128;
        const float4 v0 = R[lane], v1 = R[lane + 64];
        float s  = dot4(v0, a0) + dot4(v1, a1);
        float n2 = dot4(v0, v0) + dot4(v1, v1);
        #pragma unroll
        for (int o = 32; o > 0; o >>= 1) {
            s  += __shfl_xor(s,  o, 64);
            n2 += __shfl_xor(n2, o, 64);
        }
        const float nrm = fmaxf(sqrtf(n2), EPS_NORM_F);
        const float c   = s / (nrm * na);
        const float al  = alpha_raw[j] * 0.4f + 0.1f;
        const float num  = (1.0f - al) * c + al;
        const float den2 = (1.0f - al) * (1.0f - al) + al * al
                         + 2.0f * al * (1.0f - al) * c;
        const float cosm = num / fmaxf(sqrtf(den2), EPS_NORM_F);
        local_exp += expf(cosm / TAU_F);
    } else if (wid < 2 * n_mix) {
        const int k  = wid - n_mix;
        const float4* A = hn4 + (size_t)idx_a[k] * 128;
        const float4* B = hn4 + (size_t)idx_b[k] * 128;
        const float4 x0 = A[lane], x1 = A[lane + 64];
        const float4 y0 = B[lane], y1 = B[lane + 64];
        float sa  = dot4(x0, a0) + dot4(x1, a1);
        float sb  = dot4(y0, a0) + dot4(y1, a1);
        float d   = dot4(x0, y0) + dot4(x1, y1);
        float nA2 = dot4(x0, x0) + dot4(x1, x1);
        float nB2 = dot4(y0, y0) + dot4(y1, y1);
        #pragma unroll
        for (int o = 32; o > 0; o >>= 1) {
            sa  += __shfl_xor(sa,  o, 64);
            sb  += __shfl_xor(sb,  o, 64);
            d   += __shfl_xor(d,   o, 64);
            nA2 += __shfl_xor(nA2, o, 64);
            nB2 += __shfl_xor(nB2, o, 64);
        }
        const float nA  = fmaxf(sqrtf(nA2), EPS_NORM_F);
        const float nB  = fmaxf(sqrtf(nB2), EPS_NORM_F);
        const float ca  = sa / (nA * na);
        const float cb  = sb / (nB * na);
        const float dab = d  / (nA * nB);
        const float be  = beta_raw[k] * 0.4f + 0.3f;
        const float num  = be * ca + (1.0f - be) * cb;
        const float den2 = be * be + (1.0f - be) * (1.0f - be)
                         + 2.0f * be * (1.0f - be) * dab;
        const float cosm = num / fmaxf(sqrtf(den2), EPS_NORM_F);
        local_exp += expf(cosm / TAU_F);
    }

    // ---- Block partial -> block_sums[blockIdx.x] (no atomic, no init) ----
    __shared__ float sred[16];
    if (lane == 0) sred[wib] = local_exp;
    __syncthreads();
    if (threadIdx.x == 0) {
        float t = 0.0f;
        for (int i = 0; i < wpb; ++i) t += sred[i];
        block_sums[blockIdx.x] = (double)t;
    }
}

// -----------------------------------------------------------------------------
// Finish kernel (1 block, 1024 threads): S = sum(block_sums);
// loss = mean_i [ -log(pv_i / (pv_i + S + 1e-8)) ].
// -----------------------------------------------------------------------------
__global__ void __launch_bounds__(1024) finish_kernel(
        const double* __restrict__ block_sums, int nblocks,
        const float* __restrict__ cos_p, int n_pos,
        float* __restrict__ out) {
    __shared__ double sred[1024];
    double acc = 0.0;
    for (int i = threadIdx.x; i < nblocks; i += 1024) acc += block_sums[i];
    sred[threadIdx.x] = acc;
    __syncthreads();
    for (int s = 512; s > 0; s >>= 1) {
        if (threadIdx.x < (unsigned)s) sred[threadIdx.x] += sred[threadIdx.x + s];
        __syncthreads();
    }
    const float S = (float)sred[0];
    __syncthreads();

    double lacc = 0.0;
    for (int i = threadIdx.x; i < n_pos; i += 1024) {
        const float pv = expf(cos_p[i] / TAU_F);
        lacc += (double)(-logf(pv / (pv + S + EPS_DENOM_F)));
    }
    sred[threadIdx.x] = lacc;
    __syncthreads();
    for (int s = 512; s > 0; s >>= 1) {
        if (threadIdx.x < (unsigned)s) sred[threadIdx.x] += sred[threadIdx.x + s];
        __syncthreads();
    }
    if (threadIdx.x == 0) out[0] = (float)(sred[0] / (double)n_pos);
}

extern "C" void kernel_launch(void* const* d_in, const int* in_sizes, int n_in,
                              void* d_out, int out_size, void* d_ws, size_t ws_size,
                              hipStream_t stream) {
    const float* anchor    = (const float*)d_in[0];
    const float* positives = (const float*)d_in[1];
    const float* hardnegs  = (const float*)d_in[2];
    const int*   mix_idx   = (const int*)d_in[3];
    const int*   idx_a     = (const int*)d_in[4];
    const int*   idx_b     = (const int*)d_in[5];
    const float* alpha_raw = (const float*)d_in[6];
    const float* beta_raw  = (const float*)d_in[7];

    const int D      = in_sizes[0];          // 512
    const int n_pos  = in_sizes[1] / D;      // 8192
    const int n_hard = in_sizes[2] / D;      // 65536
    const int n_mix  = in_sizes[3];          // 64

    const int GRID = 2048;                   // 8192 waves -> 9 rows/wave exactly

    // ws layout: [0, GRID*8) block_sums | then cos_p. Both fully overwritten
    // every launch (harness poisons ws to 0xAA — no init needed).
    char*   ws         = (char*)d_ws;
    double* block_sums = (double*)ws;
    float*  cos_p      = (float*)(ws + (size_t)GRID * sizeof(double));

    main_kernel<<<GRID, 256, 0, stream>>>(anchor, positives, hardnegs,
                                          mix_idx, idx_a, idx_b,
                                          alpha_raw, beta_raw,
                                          block_sums, cos_p,
                                          n_hard, n_pos, n_mix);

    finish_kernel<<<1, 1024, 0, stream>>>(block_sums, GRID, cos_p,
                                          n_pos, (float*)d_out);
}